// Round 1
// baseline (2456.033 us; speedup 1.0000x reference)
//
#include <hip/hip_runtime.h>
#include <hip/hip_bf16.h>
#include <math.h>

typedef __attribute__((ext_vector_type(4))) float f32x4;
typedef __attribute__((ext_vector_type(8))) short s16x8;
typedef __attribute__((ext_vector_type(4))) short s16x4;

#define DEVI __device__ __forceinline__

// B=4, S=4096, D=2048, H=16, DH=128, M = B*S = 16384, K = N = 2048

DEVI unsigned short f2bf(float x) {
    unsigned int u = __builtin_bit_cast(unsigned int, x);
    u += 0x7fffu + ((u >> 16) & 1u);          // RNE
    return (unsigned short)(u >> 16);
}

DEVI f32x4 mfma16(s16x8 a, s16x8 b, f32x4 c) {
    return __builtin_amdgcn_mfma_f32_16x16x32_bf16(a, b, c, 0, 0, 0);
}

// ---------------- RoPE cos/sin tables: [4096][64] f32 each ----------------
__global__ void rope_table_kernel(float* __restrict__ cosb, float* __restrict__ sinb) {
    const int s = blockIdx.x;
    const int i = threadIdx.x;                              // 0..63
    const float inv = expf(-(float)i * (9.210340371976184f / 64.0f)); // 10000^(-i/64)
    const float ang = (float)s * inv;
    cosb[s * 64 + i] = cosf(ang);
    sinb[s * 64 + i] = sinf(ang);
}

// ---------------- GEMM: C[16384][2048] = A[16384][2048] * W[2048][2048]^T ----
// ABF16: A is bf16 (else f32).  B (weights) always f32, converted on the fly.
// EPI 0: RoPE -> bf16 [B,H,S,DH]   (Q and K projections)
// EPI 1: transpose -> bf16 [B,H,DH,S]  (V projection)
// EPI 2: f32 row-major [M][N]      (output projection -> d_out)
template <bool ABF16, int EPI>
__global__ __launch_bounds__(256, 2)
void gemm_kernel(const void* __restrict__ Ap, const float* __restrict__ Bw,
                 void* __restrict__ Cp, const float* __restrict__ cosb,
                 const float* __restrict__ sinb)
{
    constexpr int KD = 2048;
    // As/Bs: [2 buf][128 rows][32+8 pad] bf16.  EPI1 reuses as [128][136] C-tile.
    __shared__ __align__(16) unsigned short smem[20480];
    unsigned short* const As = smem;
    unsigned short* const Bs = smem + 10240;

    const int tid  = threadIdx.x;
    const int lane = tid & 63;
    const int wid  = tid >> 6;
    const int wr   = wid >> 1, wc = wid & 1;
    const int lr   = lane & 15;
    const int lkg  = lane >> 4;
    const int lk   = lkg * 8;
    const int m0   = blockIdx.x * 128;
    const int n0   = blockIdx.y * 128;

    const f32x4 zero4 = {0.f, 0.f, 0.f, 0.f};
    f32x4 acc[4][4];
#pragma unroll
    for (int i = 0; i < 4; ++i)
#pragma unroll
        for (int j = 0; j < 4; ++j) acc[i][j] = zero4;

    f32x4 aF[4], bF[4];
    s16x8 aH[2];
    const float* Af = (const float*)Ap;
    const unsigned short* Ah = (const unsigned short*)Ap;

    auto stage_load = [&](int kt) {
        const int k0 = kt * 32;
        if constexpr (!ABF16) {
#pragma unroll
            for (int i = 0; i < 4; ++i) {
                int flat = i * 256 + tid;            // 0..1023
                int r = flat >> 3, c = (flat & 7) * 4;
                aF[i] = *(const f32x4*)&Af[(size_t)(m0 + r) * KD + k0 + c];
            }
        } else {
#pragma unroll
            for (int i = 0; i < 2; ++i) {
                int flat = i * 256 + tid;            // 0..511
                int r = flat >> 2, c = (flat & 3) * 8;
                aH[i] = *(const s16x8*)&Ah[(size_t)(m0 + r) * KD + k0 + c];
            }
        }
#pragma unroll
        for (int i = 0; i < 4; ++i) {
            int flat = i * 256 + tid;
            int r = flat >> 3, c = (flat & 7) * 4;
            bF[i] = *(const f32x4*)&Bw[(size_t)(n0 + r) * KD + k0 + c];
        }
    };

    auto stage_write = [&](int buf) {
        unsigned short* Ab = As + buf * 5120;
        unsigned short* Bb = Bs + buf * 5120;
        if constexpr (!ABF16) {
#pragma unroll
            for (int i = 0; i < 4; ++i) {
                int flat = i * 256 + tid;
                int r = flat >> 3, c = (flat & 7) * 4;
                s16x4 v;
#pragma unroll
                for (int e = 0; e < 4; ++e) v[e] = (short)f2bf(aF[i][e]);
                *(s16x4*)&Ab[r * 40 + c] = v;
            }
        } else {
#pragma unroll
            for (int i = 0; i < 2; ++i) {
                int flat = i * 256 + tid;
                int r = flat >> 2, c = (flat & 3) * 8;
                *(s16x8*)&Ab[r * 40 + c] = aH[i];
            }
        }
#pragma unroll
        for (int i = 0; i < 4; ++i) {
            int flat = i * 256 + tid;
            int r = flat >> 3, c = (flat & 7) * 4;
            s16x4 v;
#pragma unroll
            for (int e = 0; e < 4; ++e) v[e] = (short)f2bf(bF[i][e]);
            *(s16x4*)&Bb[r * 40 + c] = v;
        }
    };

    const int ncol0 = wc * 32;

    auto compute = [&](int buf) {
        const unsigned short* Ab = As + buf * 5120;
        const unsigned short* Bb = Bs + buf * 5120;
        s16x8 af[4], bf[4];
#pragma unroll
        for (int mi = 0; mi < 4; ++mi)
            af[mi] = *(const s16x8*)&Ab[(wr * 64 + mi * 16 + lr) * 40 + lk];
#pragma unroll
        for (int nj = 0; nj < 4; ++nj) {
            int nc = ncol0 + (nj & 1) * 16 + (nj >> 1) * 64;   // paired cols: nj and nj+2 differ by 64
            bf[nj] = *(const s16x8*)&Bb[(nc + lr) * 40 + lk];
        }
#pragma unroll
        for (int mi = 0; mi < 4; ++mi)
#pragma unroll
            for (int nj = 0; nj < 4; ++nj)
                acc[mi][nj] = mfma16(af[mi], bf[nj], acc[mi][nj]);
    };

    stage_load(0);
    stage_write(0);
    __syncthreads();
    for (int kt = 0; kt < 64; ++kt) {
        const int cur = kt & 1;
        if (kt < 63) stage_load(kt + 1);
        compute(cur);
        if (kt < 63) stage_write(cur ^ 1);
        __syncthreads();
    }

    if constexpr (EPI == 0) {
        // RoPE epilogue -> bf16 [B,H,S,DH]; pairs (dh, dh+64) are (acc[*][nj], acc[*][nj+2])
        unsigned short* Qb = (unsigned short*)Cp;
        const int h = blockIdx.y;
#pragma unroll
        for (int mi = 0; mi < 4; ++mi) {
#pragma unroll
            for (int reg = 0; reg < 4; ++reg) {
                int mg = m0 + wr * 64 + mi * 16 + lkg * 4 + reg;
                int bb = mg >> 12, s = mg & 4095;
                size_t base = ((size_t)(bb * 16 + h) * 4096 + s) * 128;
#pragma unroll
                for (int nj = 0; nj < 2; ++nj) {
                    int dlo = wc * 32 + nj * 16 + lr;          // 0..63
                    float cv = cosb[s * 64 + dlo];
                    float sv = sinb[s * 64 + dlo];
                    float a  = acc[mi][nj][reg];
                    float b2 = acc[mi][nj + 2][reg];
                    Qb[base + dlo]      = f2bf(a * cv - b2 * sv);
                    Qb[base + dlo + 64] = f2bf(b2 * cv + a * sv);
                }
            }
        }
    } else if constexpr (EPI == 1) {
        // Transposed V epilogue -> bf16 [B,H,DH,S] via LDS tile
        unsigned short* Vt = (unsigned short*)Cp;
        const int h = blockIdx.y;
        unsigned short* Cs = smem;                 // [128][136]
#pragma unroll
        for (int mi = 0; mi < 4; ++mi)
#pragma unroll
            for (int nj = 0; nj < 4; ++nj) {
                int col = wc * 32 + (nj & 1) * 16 + (nj >> 1) * 64 + lr;
#pragma unroll
                for (int reg = 0; reg < 4; ++reg) {
                    int row = wr * 64 + mi * 16 + lkg * 4 + reg;
                    Cs[row * 136 + col] = f2bf(acc[mi][nj][reg]);
                }
            }
        __syncthreads();
        const int dh = tid >> 1;
        const int sh = (tid & 1) * 64;
        const int bb = m0 >> 12, sbase = m0 & 4095;
        size_t gbase = ((size_t)((bb * 16 + h) * 128 + dh)) * 4096 + sbase + sh;
#pragma unroll
        for (int j0 = 0; j0 < 8; ++j0) {
            s16x8 v;
#pragma unroll
            for (int e = 0; e < 8; ++e)
                v[e] = (short)Cs[(sh + j0 * 8 + e) * 136 + dh];
            *(s16x8*)&Vt[gbase + j0 * 8] = v;
        }
    } else {
        // f32 output [M][N] -> d_out
        float* Ob = (float*)Cp;
#pragma unroll
        for (int mi = 0; mi < 4; ++mi)
#pragma unroll
            for (int reg = 0; reg < 4; ++reg) {
                int mg = m0 + wr * 64 + mi * 16 + lkg * 4 + reg;
#pragma unroll
                for (int nj = 0; nj < 4; ++nj) {
                    int col = n0 + wc * 32 + (nj & 1) * 16 + (nj >> 1) * 64 + lr;
                    Ob[(size_t)mg * 2048 + col] = acc[mi][nj][reg];
                }
            }
    }
}

// ---------------- Flash attention (non-causal), bf16 MFMA ----------------
// grid (S/128=32, B*H=64), 256 threads (4 waves); wave w owns q-rows [w*32, w*32+32)
__global__ __launch_bounds__(256, 2)
void attn_kernel(const unsigned short* __restrict__ Q,
                 const unsigned short* __restrict__ Kb,
                 const unsigned short* __restrict__ Vt,
                 unsigned short* __restrict__ ctx)
{
    __shared__ __align__(16) unsigned short Ks[64][136];   // [kv][dh], +8 pad
    __shared__ __align__(16) unsigned short Vts[128][72];  // [dh][kv], +8 pad
    __shared__ __align__(16) unsigned short Ps[128][72];   // [q][kv] per-wave rows

    const int tid  = threadIdx.x;
    const int lane = tid & 63;
    const int wid  = tid >> 6;
    const int lr   = lane & 15;
    const int lkg  = lane >> 4;
    const int lk   = lkg * 8;
    const int qt   = blockIdx.x;
    const int bh   = blockIdx.y;
    const float C  = 0.12751763f;   // (1/sqrt(128)) * log2(e)

    // Q fragments in registers (A-operand), rows = this wave's 32 q-rows
    const size_t qrow0 = (size_t)bh * 4096 + qt * 128 + wid * 32;
    s16x8 qf[2][4];
#pragma unroll
    for (int mi = 0; mi < 2; ++mi)
#pragma unroll
        for (int ks = 0; ks < 4; ++ks)
            qf[mi][ks] = *(const s16x8*)&Q[(qrow0 + mi * 16 + lr) * 128 + ks * 32 + lk];

    const f32x4 zero4 = {0.f, 0.f, 0.f, 0.f};
    f32x4 accO[2][8];
#pragma unroll
    for (int mi = 0; mi < 2; ++mi)
#pragma unroll
        for (int df = 0; df < 8; ++df) accO[mi][df] = zero4;
    float mrow[2][4], lrow[2][4];
#pragma unroll
    for (int mi = 0; mi < 2; ++mi)
#pragma unroll
        for (int r = 0; r < 4; ++r) { mrow[mi][r] = -1e30f; lrow[mi][r] = 0.f; }

    const size_t kbase  = (size_t)bh * 4096;
    const size_t vtbase = (size_t)bh * 128 * 4096;

    for (int kt = 0; kt < 64; ++kt) {
        const int kv0 = kt * 64;
        __syncthreads();
        // stage K tile [64][128]
#pragma unroll
        for (int i = 0; i < 4; ++i) {
            int flat = i * 256 + tid;                // 0..1023
            int r = flat >> 4, c8 = (flat & 15) * 8;
            *(s16x8*)&Ks[r][c8] = *(const s16x8*)&Kb[(kbase + kv0 + r) * 128 + c8];
        }
        // stage V^T tile [128][64]
#pragma unroll
        for (int i = 0; i < 4; ++i) {
            int flat = i * 256 + tid;
            int r = flat >> 3, c8 = (flat & 7) * 8;
            *(s16x8*)&Vts[r][c8] = *(const s16x8*)&Vt[vtbase + (size_t)r * 4096 + kv0 + c8];
        }
        __syncthreads();

        // S = Q K^T  (per wave: 32 q-rows x 64 kv)
        f32x4 sc[2][4];
#pragma unroll
        for (int mi = 0; mi < 2; ++mi)
#pragma unroll
            for (int nf = 0; nf < 4; ++nf) sc[mi][nf] = zero4;
#pragma unroll
        for (int ks = 0; ks < 4; ++ks) {
            s16x8 kf[4];
#pragma unroll
            for (int nf = 0; nf < 4; ++nf)
                kf[nf] = *(const s16x8*)&Ks[nf * 16 + lr][ks * 32 + lk];
#pragma unroll
            for (int mi = 0; mi < 2; ++mi)
#pragma unroll
                for (int nf = 0; nf < 4; ++nf)
                    sc[mi][nf] = mfma16(qf[mi][ks], kf[nf], sc[mi][nf]);
        }

        // online softmax per q-row (row lives in one 16-lane group)
#pragma unroll
        for (int mi = 0; mi < 2; ++mi) {
#pragma unroll
            for (int reg = 0; reg < 4; ++reg) {
                float v = fmaxf(fmaxf(sc[mi][0][reg], sc[mi][1][reg]),
                                fmaxf(sc[mi][2][reg], sc[mi][3][reg])) * C;
#pragma unroll
                for (int off = 1; off < 16; off <<= 1)
                    v = fmaxf(v, __shfl_xor(v, off, 64));
                const float mold = mrow[mi][reg];
                const float mnew = fmaxf(mold, v);
                mrow[mi][reg] = mnew;
                const float f = exp2f(mold - mnew);
                float psum = 0.f;
                const int prow = wid * 32 + mi * 16 + lkg * 4 + reg;
#pragma unroll
                for (int nf = 0; nf < 4; ++nf) {
                    float p = exp2f(fmaf(sc[mi][nf][reg], C, -mnew));
                    psum += p;
                    Ps[prow][nf * 16 + lr] = f2bf(p);
                }
#pragma unroll
                for (int off = 1; off < 16; off <<= 1)
                    psum += __shfl_xor(psum, off, 64);
                lrow[mi][reg] = lrow[mi][reg] * f + psum;
#pragma unroll
                for (int df = 0; df < 8; ++df)
                    accO[mi][df][reg] *= f;
            }
        }

        // O += P V   (A = P from own-wave LDS rows, B = V^T tile)
        s16x8 pa[2][2];
#pragma unroll
        for (int mi = 0; mi < 2; ++mi)
#pragma unroll
            for (int k2 = 0; k2 < 2; ++k2)
                pa[mi][k2] = *(const s16x8*)&Ps[wid * 32 + mi * 16 + lr][k2 * 32 + lk];
#pragma unroll
        for (int df = 0; df < 8; ++df) {
#pragma unroll
            for (int k2 = 0; k2 < 2; ++k2) {
                s16x8 vf = *(const s16x8*)&Vts[df * 16 + lr][k2 * 32 + lk];
#pragma unroll
                for (int mi = 0; mi < 2; ++mi)
                    accO[mi][df] = mfma16(pa[mi][k2], vf, accO[mi][df]);
            }
        }
    }

    // epilogue: O/l -> ctx bf16 [B,S,H*DH]
    const int bb = bh >> 4, h = bh & 15;
#pragma unroll
    for (int mi = 0; mi < 2; ++mi)
#pragma unroll
        for (int reg = 0; reg < 4; ++reg) {
            const float inv = 1.0f / lrow[mi][reg];
            const int q = qt * 128 + wid * 32 + mi * 16 + lkg * 4 + reg;
            const size_t base = ((size_t)(bb * 4096 + q)) * 2048 + h * 128;
#pragma unroll
            for (int df = 0; df < 8; ++df)
                ctx[base + df * 16 + lr] = f2bf(accO[mi][df][reg] * inv);
        }
}

extern "C" void kernel_launch(void* const* d_in, const int* in_sizes, int n_in,
                              void* d_out, int out_size, void* d_ws, size_t ws_size,
                              hipStream_t stream)
{
    (void)in_sizes; (void)n_in; (void)out_size;
    const float* X  = (const float*)d_in[0];
    const float* Wq = (const float*)d_in[1];
    const float* Wk = (const float*)d_in[2];
    const float* Wv = (const float*)d_in[3];
    const float* Wo = (const float*)d_in[4];

    char* ws = (char*)d_ws;
    const size_t TBL  = 2097152;    // cos+sin tables (2 x 1 MB)
    const size_t HBUF = 67108864;   // one bf16 [B,H,S,DH] buffer

    float* cosb = (float*)ws;
    float* sinb = (float*)(ws + 1048576);

    unsigned short *Qb, *Kb, *Vtb, *Cb;
    if (ws_size >= TBL + 4 * HBUF) {
        Qb  = (unsigned short*)(ws + TBL);
        Kb  = (unsigned short*)(ws + TBL + HBUF);
        Vtb = (unsigned short*)(ws + TBL + 2 * HBUF);
        Cb  = (unsigned short*)(ws + TBL + 3 * HBUF);
    } else {
        // park Q,K in d_out (dead after attention; final GEMM overwrites d_out)
        Qb  = (unsigned short*)d_out;
        Kb  = Qb + 33554432;
        Vtb = (unsigned short*)(ws + TBL);
        Cb  = (unsigned short*)(ws + TBL + HBUF);
    }

    rope_table_kernel<<<dim3(4096), dim3(64), 0, stream>>>(cosb, sinb);
    dim3 gg(128, 16), blk(256);
    gemm_kernel<false, 0><<<gg, blk, 0, stream>>>(X, Wq, Qb, cosb, sinb);
    gemm_kernel<false, 0><<<gg, blk, 0, stream>>>(X, Wk, Kb, cosb, sinb);
    gemm_kernel<false, 1><<<gg, blk, 0, stream>>>(X, Wv, Vtb, cosb, sinb);
    attn_kernel<<<dim3(32, 64), dim3(256), 0, stream>>>(Qb, Kb, Vtb, Cb);
    gemm_kernel<true, 2><<<gg, blk, 0, stream>>>(Cb, Wo, d_out, cosb, sinb);
}

// Round 2
// 1732.143 us; speedup vs baseline: 1.4179x; 1.4179x over previous
//
#include <hip/hip_runtime.h>
#include <hip/hip_bf16.h>
#include <math.h>

typedef __attribute__((ext_vector_type(4)))  float f32x4;
typedef __attribute__((ext_vector_type(16))) float f32x16;
typedef __attribute__((ext_vector_type(8)))  short s16x8;
typedef __attribute__((ext_vector_type(4)))  short s16x4;
typedef __attribute__((ext_vector_type(4)))  int   i32x4;

#define DEVI __device__ __forceinline__

// B=4, S=4096, D=2048, H=16, DH=128, M = B*S = 16384, K = N = 2048

DEVI unsigned short f2bf(float x) {
    unsigned int u = __builtin_bit_cast(unsigned int, x);
    u += 0x7fffu + ((u >> 16) & 1u);          // RNE
    return (unsigned short)(u >> 16);
}

DEVI f32x4 mfma16(s16x8 a, s16x8 b, f32x4 c) {
    return __builtin_amdgcn_mfma_f32_16x16x32_bf16(a, b, c, 0, 0, 0);
}
DEVI f32x16 mfma32(s16x8 a, s16x8 b, f32x16 c) {
    return __builtin_amdgcn_mfma_f32_32x32x16_bf16(a, b, c, 0, 0, 0);
}
DEVI int cvtpk(float lo, float hi) {
    int r; asm("v_cvt_pk_bf16_f32 %0, %1, %2" : "=v"(r) : "v"(lo), "v"(hi)); return r;
}
DEVI void plswap(int& a, int& b) {   // swap a.hi-lanes <-> b.lo-lanes (rows 1<->2)
    asm volatile("v_permlane32_swap_b32 %0, %1" : "+v"(a), "+v"(b));
}
DEVI void gload16(const void* g, void* l) {
    __builtin_amdgcn_global_load_lds(
        (const __attribute__((address_space(1))) void*)g,
        (__attribute__((address_space(3))) void*)l, 16, 0, 0);
}

// ---------------- RoPE cos/sin tables: [4096][64] f32 each ----------------
__global__ void rope_table_kernel(float* __restrict__ cosb, float* __restrict__ sinb) {
    const int s = blockIdx.x;
    const int i = threadIdx.x;                              // 0..63
    const float inv = expf(-(float)i * (9.210340371976184f / 64.0f)); // 10000^(-i/64)
    const float ang = (float)s * inv;
    cosb[s * 64 + i] = cosf(ang);
    sinb[s * 64 + i] = sinf(ang);
}

// ---------------- GEMM: C[16384][2048] = A[16384][2048] * W[2048][2048]^T ----
// ABF16: A is bf16 (else f32).  B (weights) always f32, converted on the fly.
// EPI 0: RoPE -> bf16 [B,H,S,DH] scaled by oscale  (Q and K projections)
// EPI 1: transpose -> bf16 [B,H,DH,S]  (V projection)
// EPI 2: f32 row-major [M][N]      (output projection -> d_out)
template <bool ABF16, int EPI>
__global__ __launch_bounds__(256, 2)
void gemm_kernel(const void* __restrict__ Ap, const float* __restrict__ Bw,
                 void* __restrict__ Cp, const float* __restrict__ cosb,
                 const float* __restrict__ sinb, float oscale)
{
    constexpr int KD = 2048;
    __shared__ __align__(16) unsigned short smem[20480];
    unsigned short* const As = smem;
    unsigned short* const Bs = smem + 10240;

    const int tid  = threadIdx.x;
    const int lane = tid & 63;
    const int wid  = tid >> 6;
    const int wr   = wid >> 1, wc = wid & 1;
    const int lr   = lane & 15;
    const int lkg  = lane >> 4;
    const int lk   = lkg * 8;
    const int m0   = blockIdx.x * 128;
    const int n0   = blockIdx.y * 128;

    const f32x4 zero4 = {0.f, 0.f, 0.f, 0.f};
    f32x4 acc[4][4];
#pragma unroll
    for (int i = 0; i < 4; ++i)
#pragma unroll
        for (int j = 0; j < 4; ++j) acc[i][j] = zero4;

    f32x4 aF[4], bF[4];
    s16x8 aH[2];
    const float* Af = (const float*)Ap;
    const unsigned short* Ah = (const unsigned short*)Ap;

    auto stage_load = [&](int kt) {
        const int k0 = kt * 32;
        if constexpr (!ABF16) {
#pragma unroll
            for (int i = 0; i < 4; ++i) {
                int flat = i * 256 + tid;
                int r = flat >> 3, c = (flat & 7) * 4;
                aF[i] = *(const f32x4*)&Af[(size_t)(m0 + r) * KD + k0 + c];
            }
        } else {
#pragma unroll
            for (int i = 0; i < 2; ++i) {
                int flat = i * 256 + tid;
                int r = flat >> 2, c = (flat & 3) * 8;
                aH[i] = *(const s16x8*)&Ah[(size_t)(m0 + r) * KD + k0 + c];
            }
        }
#pragma unroll
        for (int i = 0; i < 4; ++i) {
            int flat = i * 256 + tid;
            int r = flat >> 3, c = (flat & 7) * 4;
            bF[i] = *(const f32x4*)&Bw[(size_t)(n0 + r) * KD + k0 + c];
        }
    };

    auto stage_write = [&](int buf) {
        unsigned short* Ab = As + buf * 5120;
        unsigned short* Bb = Bs + buf * 5120;
        if constexpr (!ABF16) {
#pragma unroll
            for (int i = 0; i < 4; ++i) {
                int flat = i * 256 + tid;
                int r = flat >> 3, c = (flat & 7) * 4;
                s16x4 v;
#pragma unroll
                for (int e = 0; e < 4; ++e) v[e] = (short)f2bf(aF[i][e]);
                *(s16x4*)&Ab[r * 40 + c] = v;
            }
        } else {
#pragma unroll
            for (int i = 0; i < 2; ++i) {
                int flat = i * 256 + tid;
                int r = flat >> 2, c = (flat & 3) * 8;
                *(s16x8*)&Ab[r * 40 + c] = aH[i];
            }
        }
#pragma unroll
        for (int i = 0; i < 4; ++i) {
            int flat = i * 256 + tid;
            int r = flat >> 3, c = (flat & 7) * 4;
            s16x4 v;
#pragma unroll
            for (int e = 0; e < 4; ++e) v[e] = (short)f2bf(bF[i][e]);
            *(s16x4*)&Bb[r * 40 + c] = v;
        }
    };

    const int ncol0 = wc * 32;

    auto compute = [&](int buf) {
        const unsigned short* Ab = As + buf * 5120;
        const unsigned short* Bb = Bs + buf * 5120;
        s16x8 af[4], bf[4];
#pragma unroll
        for (int mi = 0; mi < 4; ++mi)
            af[mi] = *(const s16x8*)&Ab[(wr * 64 + mi * 16 + lr) * 40 + lk];
#pragma unroll
        for (int nj = 0; nj < 4; ++nj) {
            int nc = ncol0 + (nj & 1) * 16 + (nj >> 1) * 64;
            bf[nj] = *(const s16x8*)&Bb[(nc + lr) * 40 + lk];
        }
#pragma unroll
        for (int mi = 0; mi < 4; ++mi)
#pragma unroll
            for (int nj = 0; nj < 4; ++nj)
                acc[mi][nj] = mfma16(af[mi], bf[nj], acc[mi][nj]);
    };

    stage_load(0);
    stage_write(0);
    __syncthreads();
    for (int kt = 0; kt < 64; ++kt) {
        const int cur = kt & 1;
        if (kt < 63) stage_load(kt + 1);
        compute(cur);
        if (kt < 63) stage_write(cur ^ 1);
        __syncthreads();
    }

    if constexpr (EPI == 0) {
        unsigned short* Qb = (unsigned short*)Cp;
        const int h = blockIdx.y;
#pragma unroll
        for (int mi = 0; mi < 4; ++mi) {
#pragma unroll
            for (int reg = 0; reg < 4; ++reg) {
                int mg = m0 + wr * 64 + mi * 16 + lkg * 4 + reg;
                int bb = mg >> 12, s = mg & 4095;
                size_t base = ((size_t)(bb * 16 + h) * 4096 + s) * 128;
#pragma unroll
                for (int nj = 0; nj < 2; ++nj) {
                    int dlo = wc * 32 + nj * 16 + lr;
                    float cv = cosb[s * 64 + dlo];
                    float sv = sinb[s * 64 + dlo];
                    float a  = acc[mi][nj][reg];
                    float b2 = acc[mi][nj + 2][reg];
                    Qb[base + dlo]      = f2bf((a * cv - b2 * sv) * oscale);
                    Qb[base + dlo + 64] = f2bf((b2 * cv + a * sv) * oscale);
                }
            }
        }
    } else if constexpr (EPI == 1) {
        unsigned short* Vt = (unsigned short*)Cp;
        const int h = blockIdx.y;
        unsigned short* Cs = smem;                 // [128][136]
#pragma unroll
        for (int mi = 0; mi < 4; ++mi)
#pragma unroll
            for (int nj = 0; nj < 4; ++nj) {
                int col = wc * 32 + (nj & 1) * 16 + (nj >> 1) * 64 + lr;
#pragma unroll
                for (int reg = 0; reg < 4; ++reg) {
                    int row = wr * 64 + mi * 16 + lkg * 4 + reg;
                    Cs[row * 136 + col] = f2bf(acc[mi][nj][reg]);
                }
            }
        __syncthreads();
        const int dh = tid >> 1;
        const int sh = (tid & 1) * 64;
        const int bb = m0 >> 12, sbase = m0 & 4095;
        size_t gbase = ((size_t)((bb * 16 + h) * 128 + dh)) * 4096 + sbase + sh;
#pragma unroll
        for (int j0 = 0; j0 < 8; ++j0) {
            s16x8 v;
#pragma unroll
            for (int e = 0; e < 8; ++e)
                v[e] = (short)Cs[(sh + j0 * 8 + e) * 136 + dh];
            *(s16x8*)&Vt[gbase + j0 * 8] = v;
        }
    } else {
        float* Ob = (float*)Cp;
#pragma unroll
        for (int mi = 0; mi < 4; ++mi)
#pragma unroll
            for (int reg = 0; reg < 4; ++reg) {
                int mg = m0 + wr * 64 + mi * 16 + lkg * 4 + reg;
#pragma unroll
                for (int nj = 0; nj < 4; ++nj) {
                    int col = n0 + wc * 32 + (nj & 1) * 16 + (nj >> 1) * 64 + lr;
                    Ob[(size_t)mg * 2048 + col] = acc[mi][nj][reg];
                }
            }
    }
}

// ---------------- Flash attention: 8 waves x 32 q-rows, KVBLK=64, 32x32 MFMA ----
// Swapped operands: S^T = mfma(K, Q), O^T = mfma(V^T, P).  P stays in registers
// (cvt_pk_bf16 + permlane32_swap).  K/V^T tiles double-buffered in LDS via
// global_load_lds with pre-swizzled global source (byte ^= (row&7)<<4).
// Q prescaled by (1/sqrt(128))*log2(e) in the Q-proj epilogue -> p = exp2(s - m).
__global__ __launch_bounds__(512, 2)
void attn_kernel(const unsigned short* __restrict__ Q,
                 const unsigned short* __restrict__ Kb,
                 const unsigned short* __restrict__ Vt,
                 unsigned short* __restrict__ ctx)
{
    __shared__ __align__(16) char smem[65536];   // 2 x (16KB K + 16KB V^T)

    const int tid  = threadIdx.x;
    const int lane = tid & 63;
    const int wid  = tid >> 6;        // 0..7
    const int l31  = lane & 31;
    const int h    = lane >> 5;       // 0/1
    const int qt   = blockIdx.x;      // 0..15 (256 q-rows per block)
    const int bh   = blockIdx.y;      // 0..63

    const size_t kbase  = (size_t)bh * 4096;
    const size_t vtbase = (size_t)bh * 128 * 4096;

    // Q fragments (B-operand of swapped QK^T): lane holds Q[q=l31][dh=16ks+8h+e]
    const size_t qrow = kbase + (size_t)qt * 256 + wid * 32 + l31;
    s16x8 qf[8];
#pragma unroll
    for (int ks = 0; ks < 8; ++ks)
        qf[ks] = *(const s16x8*)&Q[qrow * 128 + ks * 16 + h * 8];

    const f32x16 Z16 = {0,0,0,0,0,0,0,0,0,0,0,0,0,0,0,0};
    f32x16 accO[4];                   // O^T[dh=32mf+rowmap][q=l31]
    accO[0] = Z16; accO[1] = Z16; accO[2] = Z16; accO[3] = Z16;
    float m = -1e30f, lsum = 0.f;

    // stage tile t into buffer buf: K[64][128] + V^T[128][64] bf16, swizzled
    auto stage = [&](int buf, int t) {
        const int kv0 = t * 64;
        char* kdst = smem + buf * 32768;
        char* vdst = kdst + 16384;
#pragma unroll
        for (int c = 0; c < 2; ++c) {
            {   // K: rows are kv (256 B each)
                int r   = wid * 8 + c * 4 + (lane >> 4);
                int col = (lane * 16) & 255;
                int cs  = col ^ ((r & 7) << 4);
                gload16(&Kb[(kbase + kv0 + r) * 128 + (cs >> 1)],
                        kdst + wid * 2048 + c * 1024);
            }
            {   // V^T: rows are dh (128 B each)
                int r   = wid * 16 + c * 8 + (lane >> 3);
                int col = (lane * 16) & 127;
                int cs  = col ^ ((r & 7) << 4);
                gload16(&Vt[vtbase + (size_t)r * 4096 + kv0 + (cs >> 1)],
                        vdst + wid * 2048 + c * 1024);
            }
        }
    };

    const int swz = (l31 & 7) << 4;

    stage(0, 0);
    __syncthreads();

    for (int t = 0; t < 64; ++t) {
        const int buf = t & 1;
        if (t < 63) stage(buf ^ 1, t + 1);

        const char* kb = smem + buf * 32768;
        const char* vb = kb + 16384;

        // S^T = K Q^T : two 32x32 blocks over kv
        f32x16 sc0 = Z16, sc1 = Z16;
#pragma unroll
        for (int ks = 0; ks < 8; ++ks) {
            s16x8 k0 = *(const s16x8*)(kb + ((l31 * 256 + ks * 32 + h * 16) ^ swz));
            s16x8 k1 = *(const s16x8*)(kb + (((l31 + 32) * 256 + ks * 32 + h * 16) ^ swz));
            sc0 = mfma32(k0, qf[ks], sc0);
            sc1 = mfma32(k1, qf[ks], sc1);
        }

        // online softmax, lane-local (lane q=l31; partner l^32 holds other 32 kv)
        float tm = sc0[0];
#pragma unroll
        for (int i = 1; i < 16; ++i) tm = fmaxf(tm, sc0[i]);
#pragma unroll
        for (int i = 0; i < 16; ++i) tm = fmaxf(tm, sc1[i]);
        tm = fmaxf(tm, __shfl_xor(tm, 32, 64));

        if (!__all(tm - m <= 8.0f)) {             // defer-max (THR=8 in log2)
            const float mnew = fmaxf(m, tm);
            const float f = exp2f(m - mnew);
            lsum *= f;
            accO[0] *= f; accO[1] *= f; accO[2] *= f; accO[3] *= f;
            m = mnew;
        }

        float p[32];
        float ps = 0.f;
#pragma unroll
        for (int i = 0; i < 16; ++i) { p[i] = exp2f(sc0[i] - m); ps += p[i]; }
#pragma unroll
        for (int i = 0; i < 16; ++i) { p[16 + i] = exp2f(sc1[i] - m); ps += p[16 + i]; }
        ps += __shfl_xor(ps, 32, 64);
        lsum += ps;

        // pack P -> bf16 B-fragments (kv-major), 16 cvt_pk + 8 permlane32_swap
        s16x8 pb[4];
#pragma unroll
        for (int g = 0; g < 4; ++g) {
            int a0 = cvtpk(p[g * 8 + 0], p[g * 8 + 1]);
            int a1 = cvtpk(p[g * 8 + 2], p[g * 8 + 3]);
            int b0 = cvtpk(p[g * 8 + 4], p[g * 8 + 5]);
            int b1 = cvtpk(p[g * 8 + 6], p[g * 8 + 7]);
            plswap(a0, b0); plswap(a1, b1);
            i32x4 w = {a0, a1, b0, b1};
            pb[g] = __builtin_bit_cast(s16x8, w);
        }

        // O^T += V^T P : A = V^T frag (row=dh), B = pb (col=q)
#pragma unroll
        for (int mf = 0; mf < 4; ++mf) {
            const int rowb = (mf * 32 + l31) * 128;
#pragma unroll
            for (int ks = 0; ks < 4; ++ks) {
                s16x8 vf = *(const s16x8*)(vb + ((rowb + ks * 32 + h * 16) ^ swz));
                accO[mf] = mfma32(vf, pb[ks], accO[mf]);
            }
        }

        __syncthreads();
    }

    // epilogue: per-wave LDS transpose (private 32x34-short patch), coalesced write
    const float invl = 1.0f / lsum;
    accO[0] *= invl; accO[1] *= invl; accO[2] *= invl; accO[3] *= invl;

    unsigned short* tw = (unsigned short*)smem + wid * 1088;   // [32][34] shorts
    const int bb = bh >> 4, hh = bh & 15;
    const size_t cbase = ((size_t)(bb * 4096 + qt * 256 + wid * 32 + l31)) * 2048 + hh * 128;
#pragma unroll
    for (int mf = 0; mf < 4; ++mf) {
#pragma unroll
        for (int reg = 0; reg < 16; ++reg) {
            int d = (reg & 3) + 8 * (reg >> 2) + 4 * h;
            tw[d * 34 + l31] = f2bf(accO[mf][reg]);
        }
        s16x8 o0, o1;
#pragma unroll
        for (int dd = 0; dd < 8; ++dd) {
            o0[dd] = (short)tw[(h * 16 + dd) * 34 + l31];
            o1[dd] = (short)tw[(h * 16 + 8 + dd) * 34 + l31];
        }
        *(s16x8*)&ctx[cbase + mf * 32 + h * 16]     = o0;
        *(s16x8*)&ctx[cbase + mf * 32 + h * 16 + 8] = o1;
    }
}

extern "C" void kernel_launch(void* const* d_in, const int* in_sizes, int n_in,
                              void* d_out, int out_size, void* d_ws, size_t ws_size,
                              hipStream_t stream)
{
    (void)in_sizes; (void)n_in; (void)out_size;
    const float* X  = (const float*)d_in[0];
    const float* Wq = (const float*)d_in[1];
    const float* Wk = (const float*)d_in[2];
    const float* Wv = (const float*)d_in[3];
    const float* Wo = (const float*)d_in[4];

    char* ws = (char*)d_ws;
    const size_t TBL  = 2097152;    // cos+sin tables (2 x 1 MB)
    const size_t HBUF = 67108864;   // one bf16 [B,H,S,DH] buffer

    float* cosb = (float*)ws;
    float* sinb = (float*)(ws + 1048576);

    unsigned short *Qb, *Kb, *Vtb, *Cb;
    if (ws_size >= TBL + 4 * HBUF) {
        Qb  = (unsigned short*)(ws + TBL);
        Kb  = (unsigned short*)(ws + TBL + HBUF);
        Vtb = (unsigned short*)(ws + TBL + 2 * HBUF);
        Cb  = (unsigned short*)(ws + TBL + 3 * HBUF);
    } else {
        // park Q,K in d_out (dead after attention; final GEMM overwrites d_out)
        Qb  = (unsigned short*)d_out;
        Kb  = Qb + 33554432;
        Vtb = (unsigned short*)(ws + TBL);
        Cb  = (unsigned short*)(ws + TBL + HBUF);
    }

    const float QSCALE = 0.12751763f;   // (1/sqrt(128)) * log2(e)

    rope_table_kernel<<<dim3(4096), dim3(64), 0, stream>>>(cosb, sinb);
    dim3 gg(128, 16), blk(256);
    gemm_kernel<false, 0><<<gg, blk, 0, stream>>>(X, Wq, Qb, cosb, sinb, QSCALE);
    gemm_kernel<false, 0><<<gg, blk, 0, stream>>>(X, Wk, Kb, cosb, sinb, 1.0f);
    gemm_kernel<false, 1><<<gg, blk, 0, stream>>>(X, Wv, Vtb, cosb, sinb, 1.0f);
    attn_kernel<<<dim3(16, 64), dim3(512), 0, stream>>>(Qb, Kb, Vtb, Cb);
    gemm_kernel<true, 2><<<gg, blk, 0, stream>>>(Cb, Wo, d_out, cosb, sinb, 1.0f);
}

// Round 3
// 1429.762 us; speedup vs baseline: 1.7178x; 1.2115x over previous
//
#include <hip/hip_runtime.h>
#include <hip/hip_bf16.h>
#include <math.h>

typedef __attribute__((ext_vector_type(4)))  float f32x4;
typedef __attribute__((ext_vector_type(16))) float f32x16;
typedef __attribute__((ext_vector_type(8)))  short s16x8;
typedef __attribute__((ext_vector_type(4)))  short s16x4;
typedef __attribute__((ext_vector_type(4)))  int   i32x4;

#define DEVI __device__ __forceinline__

// B=4, S=4096, D=2048, H=16, DH=128, M = B*S = 16384, K = N = 2048

DEVI unsigned short f2bf(float x) {
    unsigned int u = __builtin_bit_cast(unsigned int, x);
    u += 0x7fffu + ((u >> 16) & 1u);          // RNE
    return (unsigned short)(u >> 16);
}

DEVI f32x4 mfma16(s16x8 a, s16x8 b, f32x4 c) {
    return __builtin_amdgcn_mfma_f32_16x16x32_bf16(a, b, c, 0, 0, 0);
}
DEVI f32x16 mfma32(s16x8 a, s16x8 b, f32x16 c) {
    return __builtin_amdgcn_mfma_f32_32x32x16_bf16(a, b, c, 0, 0, 0);
}
DEVI int cvtpk(float lo, float hi) {
    int r; asm("v_cvt_pk_bf16_f32 %0, %1, %2" : "=v"(r) : "v"(lo), "v"(hi)); return r;
}
DEVI void plswap(int& a, int& b) {
    asm volatile("v_permlane32_swap_b32 %0, %1" : "+v"(a), "+v"(b));
}
DEVI void gload16(const void* g, void* l) {
    __builtin_amdgcn_global_load_lds(
        (const __attribute__((address_space(1))) void*)g,
        (__attribute__((address_space(3))) void*)l, 16, 0, 0);
}

// ---------------- f32 -> bf16 flat convert (8 elems/thread/iter) ----------------
__global__ __launch_bounds__(256)
void cvt_kernel(const float* __restrict__ in, unsigned short* __restrict__ out, int n8) {
    int i = blockIdx.x * 256 + threadIdx.x;
    const int stride = gridDim.x * 256;
    for (; i < n8; i += stride) {
        f32x4 a = ((const f32x4*)in)[i * 2];
        f32x4 b = ((const f32x4*)in)[i * 2 + 1];
        s16x8 o;
#pragma unroll
        for (int e = 0; e < 4; ++e) o[e] = (short)f2bf(a[e]);
#pragma unroll
        for (int e = 0; e < 4; ++e) o[4 + e] = (short)f2bf(b[e]);
        *(s16x8*)&out[(size_t)i * 8] = o;
    }
}

// ---------------- RoPE cos/sin tables: [4096][64] f32 each ----------------
__global__ void rope_table_kernel(float* __restrict__ cosb, float* __restrict__ sinb) {
    const int s = blockIdx.x;
    const int i = threadIdx.x;                              // 0..63
    const float inv = expf(-(float)i * (9.210340371976184f / 64.0f)); // 10000^(-i/64)
    const float ang = (float)s * inv;
    cosb[s * 64 + i] = cosf(ang);
    sinb[s * 64 + i] = sinf(ang);
}

// ---------------- GEMM: C[16384][2048] = A[16384][2048] * W[2048][2048]^T ----
// AB16/WB16: operand is bf16.  AB16&&WB16 -> global_load_lds staging (m97 path).
// EPI 0: RoPE -> bf16 [B,H,S,DH] scaled by oscale  (Q and K projections)
// EPI 1: transpose -> bf16 [B,H,DH,S]  (V projection)
// EPI 2: f32 row-major [M][N]      (output projection -> d_out)
template <bool AB16, bool WB16, int EPI>
__global__ __launch_bounds__(256, 2)
void gemm_kernel(const void* __restrict__ Ap, const void* __restrict__ Bw,
                 void* __restrict__ Cp, const float* __restrict__ cosb,
                 const float* __restrict__ sinb, float oscale)
{
    constexpr bool GL = AB16 && WB16;
    static_assert(GL || !WB16, "non-GL path stages W as f32");
    constexpr int KD = 2048;
    __shared__ __align__(16) unsigned short smem[GL ? 17408 : 20480];

    const int tid  = threadIdx.x;
    const int lane = tid & 63;
    const int wid  = tid >> 6;
    const int wr   = wid >> 1, wc = wid & 1;
    const int lr   = lane & 15;
    const int lkg  = lane >> 4;
    const int lk   = lkg * 8;
    const int m0   = blockIdx.x * 128;
    const int n0   = blockIdx.y * 128;

    const f32x4 zero4 = {0.f, 0.f, 0.f, 0.f};
    f32x4 acc[4][4];
#pragma unroll
    for (int i = 0; i < 4; ++i)
#pragma unroll
        for (int j = 0; j < 4; ++j) acc[i][j] = zero4;

    const int ncol0 = wc * 32;

    if constexpr (GL) {
        // ---- m97-style: global_load_lds width-16, linear [128][32] tiles ----
        const unsigned short* Ah = (const unsigned short*)Ap;
        const unsigned short* Wh = (const unsigned short*)Bw;
        auto stageG = [&](int kt, int buf) {
            const int k0 = kt * 32;
            unsigned short* Ab = smem + buf * 4096;
            unsigned short* Bb = smem + 8192 + buf * 4096;
#pragma unroll
            for (int i = 0; i < 2; ++i) {
                int flat = i * 256 + tid;               // 0..511
                int r = flat >> 2, c = (flat & 3) * 8;
                gload16(&Ah[(size_t)(m0 + r) * KD + k0 + c], Ab + flat * 8);
                gload16(&Wh[(size_t)(n0 + r) * KD + k0 + c], Bb + flat * 8);
            }
        };
        auto computeG = [&](int buf) {
            const unsigned short* Ab = smem + buf * 4096;
            const unsigned short* Bb = smem + 8192 + buf * 4096;
            s16x8 af[4], bf[4];
#pragma unroll
            for (int mi = 0; mi < 4; ++mi)
                af[mi] = *(const s16x8*)&Ab[(wr * 64 + mi * 16 + lr) * 32 + lk];
#pragma unroll
            for (int nj = 0; nj < 4; ++nj) {
                int nc = ncol0 + (nj & 1) * 16 + (nj >> 1) * 64;
                bf[nj] = *(const s16x8*)&Bb[(nc + lr) * 32 + lk];
            }
#pragma unroll
            for (int mi = 0; mi < 4; ++mi)
#pragma unroll
                for (int nj = 0; nj < 4; ++nj)
                    acc[mi][nj] = mfma16(af[mi], bf[nj], acc[mi][nj]);
        };
        stageG(0, 0);
        __syncthreads();
        for (int kt = 0; kt < 64; ++kt) {
            const int cur = kt & 1;
            if (kt < 63) stageG(kt + 1, cur ^ 1);
            computeG(cur);
            __syncthreads();
        }
    } else {
        // ---- legacy reg-staged path (f32 W; A f32 or bf16), padded LDS ----
        unsigned short* const As = smem;
        unsigned short* const Bs = smem + 10240;
        f32x4 aF[4], bF[4];
        s16x8 aH[2];
        const float* Af = (const float*)Ap;
        const unsigned short* Ah = (const unsigned short*)Ap;
        const float* Wf = (const float*)Bw;

        auto stage_load = [&](int kt) {
            const int k0 = kt * 32;
            if constexpr (!AB16) {
#pragma unroll
                for (int i = 0; i < 4; ++i) {
                    int flat = i * 256 + tid;
                    int r = flat >> 3, c = (flat & 7) * 4;
                    aF[i] = *(const f32x4*)&Af[(size_t)(m0 + r) * KD + k0 + c];
                }
            } else {
#pragma unroll
                for (int i = 0; i < 2; ++i) {
                    int flat = i * 256 + tid;
                    int r = flat >> 2, c = (flat & 3) * 8;
                    aH[i] = *(const s16x8*)&Ah[(size_t)(m0 + r) * KD + k0 + c];
                }
            }
#pragma unroll
            for (int i = 0; i < 4; ++i) {
                int flat = i * 256 + tid;
                int r = flat >> 3, c = (flat & 7) * 4;
                bF[i] = *(const f32x4*)&Wf[(size_t)(n0 + r) * KD + k0 + c];
            }
        };
        auto stage_write = [&](int buf) {
            unsigned short* Ab = As + buf * 5120;
            unsigned short* Bb = Bs + buf * 5120;
            if constexpr (!AB16) {
#pragma unroll
                for (int i = 0; i < 4; ++i) {
                    int flat = i * 256 + tid;
                    int r = flat >> 3, c = (flat & 7) * 4;
                    s16x4 v;
#pragma unroll
                    for (int e = 0; e < 4; ++e) v[e] = (short)f2bf(aF[i][e]);
                    *(s16x4*)&Ab[r * 40 + c] = v;
                }
            } else {
#pragma unroll
                for (int i = 0; i < 2; ++i) {
                    int flat = i * 256 + tid;
                    int r = flat >> 2, c = (flat & 3) * 8;
                    *(s16x8*)&Ab[r * 40 + c] = aH[i];
                }
            }
#pragma unroll
            for (int i = 0; i < 4; ++i) {
                int flat = i * 256 + tid;
                int r = flat >> 3, c = (flat & 7) * 4;
                s16x4 v;
#pragma unroll
                for (int e = 0; e < 4; ++e) v[e] = (short)f2bf(bF[i][e]);
                *(s16x4*)&Bb[r * 40 + c] = v;
            }
        };
        auto compute = [&](int buf) {
            const unsigned short* Ab = As + buf * 5120;
            const unsigned short* Bb = Bs + buf * 5120;
            s16x8 af[4], bf[4];
#pragma unroll
            for (int mi = 0; mi < 4; ++mi)
                af[mi] = *(const s16x8*)&Ab[(wr * 64 + mi * 16 + lr) * 40 + lk];
#pragma unroll
            for (int nj = 0; nj < 4; ++nj) {
                int nc = ncol0 + (nj & 1) * 16 + (nj >> 1) * 64;
                bf[nj] = *(const s16x8*)&Bb[(nc + lr) * 40 + lk];
            }
#pragma unroll
            for (int mi = 0; mi < 4; ++mi)
#pragma unroll
                for (int nj = 0; nj < 4; ++nj)
                    acc[mi][nj] = mfma16(af[mi], bf[nj], acc[mi][nj]);
        };
        stage_load(0);
        stage_write(0);
        __syncthreads();
        for (int kt = 0; kt < 64; ++kt) {
            const int cur = kt & 1;
            if (kt < 63) stage_load(kt + 1);
            compute(cur);
            if (kt < 63) stage_write(cur ^ 1);
            __syncthreads();
        }
    }

    if constexpr (EPI == 0) {
        unsigned short* Qb = (unsigned short*)Cp;
        const int h = blockIdx.y;
#pragma unroll
        for (int mi = 0; mi < 4; ++mi) {
#pragma unroll
            for (int reg = 0; reg < 4; ++reg) {
                int mg = m0 + wr * 64 + mi * 16 + lkg * 4 + reg;
                int bb = mg >> 12, s = mg & 4095;
                size_t base = ((size_t)(bb * 16 + h) * 4096 + s) * 128;
#pragma unroll
                for (int nj = 0; nj < 2; ++nj) {
                    int dlo = wc * 32 + nj * 16 + lr;
                    float cv = cosb[s * 64 + dlo];
                    float sv = sinb[s * 64 + dlo];
                    float a  = acc[mi][nj][reg];
                    float b2 = acc[mi][nj + 2][reg];
                    Qb[base + dlo]      = f2bf((a * cv - b2 * sv) * oscale);
                    Qb[base + dlo + 64] = f2bf((b2 * cv + a * sv) * oscale);
                }
            }
        }
    } else if constexpr (EPI == 1) {
        unsigned short* Vt = (unsigned short*)Cp;
        const int h = blockIdx.y;
        unsigned short* Cs = smem;                 // [128][136]
        __syncthreads();
#pragma unroll
        for (int mi = 0; mi < 4; ++mi)
#pragma unroll
            for (int nj = 0; nj < 4; ++nj) {
                int col = wc * 32 + (nj & 1) * 16 + (nj >> 1) * 64 + lr;
#pragma unroll
                for (int reg = 0; reg < 4; ++reg) {
                    int row = wr * 64 + mi * 16 + lkg * 4 + reg;
                    Cs[row * 136 + col] = f2bf(acc[mi][nj][reg]);
                }
            }
        __syncthreads();
        const int dh = tid >> 1;
        const int sh = (tid & 1) * 64;
        const int bb = m0 >> 12, sbase = m0 & 4095;
        size_t gbase = ((size_t)((bb * 16 + h) * 128 + dh)) * 4096 + sbase + sh;
#pragma unroll
        for (int j0 = 0; j0 < 8; ++j0) {
            s16x8 v;
#pragma unroll
            for (int e = 0; e < 8; ++e)
                v[e] = (short)Cs[(sh + j0 * 8 + e) * 136 + dh];
            *(s16x8*)&Vt[gbase + j0 * 8] = v;
        }
    } else {
        float* Ob = (float*)Cp;
#pragma unroll
        for (int mi = 0; mi < 4; ++mi)
#pragma unroll
            for (int reg = 0; reg < 4; ++reg) {
                int mg = m0 + wr * 64 + mi * 16 + lkg * 4 + reg;
#pragma unroll
                for (int nj = 0; nj < 4; ++nj) {
                    int col = n0 + wc * 32 + (nj & 1) * 16 + (nj >> 1) * 64 + lr;
                    Ob[(size_t)mg * 2048 + col] = acc[mi][nj][reg];
                }
            }
    }
}

// ---------------- Flash attention: 8 waves x 32 q-rows, KVBLK=64, 32x32 MFMA ----
__global__ __launch_bounds__(512, 2)
void attn_kernel(const unsigned short* __restrict__ Q,
                 const unsigned short* __restrict__ Kb,
                 const unsigned short* __restrict__ Vt,
                 unsigned short* __restrict__ ctx)
{
    __shared__ __align__(16) char smem[65536];   // 2 x (16KB K + 16KB V^T)

    const int tid  = threadIdx.x;
    const int lane = tid & 63;
    const int wid  = tid >> 6;        // 0..7
    const int l31  = lane & 31;
    const int h    = lane >> 5;       // 0/1
    const int qt   = blockIdx.x;      // 0..15 (256 q-rows per block)
    const int bh   = blockIdx.y;      // 0..63

    const size_t kbase  = (size_t)bh * 4096;
    const size_t vtbase = (size_t)bh * 128 * 4096;

    const size_t qrow = kbase + (size_t)qt * 256 + wid * 32 + l31;
    s16x8 qf[8];
#pragma unroll
    for (int ks = 0; ks < 8; ++ks)
        qf[ks] = *(const s16x8*)&Q[qrow * 128 + ks * 16 + h * 8];

    const f32x16 Z16 = {0,0,0,0,0,0,0,0,0,0,0,0,0,0,0,0};
    f32x16 accO[4];
    accO[0] = Z16; accO[1] = Z16; accO[2] = Z16; accO[3] = Z16;
    float m = -1e30f, lsum = 0.f;

    auto stage = [&](int buf, int t) {
        const int kv0 = t * 64;
        char* kdst = smem + buf * 32768;
        char* vdst = kdst + 16384;
#pragma unroll
        for (int c = 0; c < 2; ++c) {
            {   // K: rows are kv (256 B each)
                int r   = wid * 8 + c * 4 + (lane >> 4);
                int col = (lane * 16) & 255;
                int cs  = col ^ ((r & 7) << 4);
                gload16(&Kb[(kbase + kv0 + r) * 128 + (cs >> 1)],
                        kdst + wid * 2048 + c * 1024);
            }
            {   // V^T: rows are dh (128 B each)
                int r   = wid * 16 + c * 8 + (lane >> 3);
                int col = (lane * 16) & 127;
                int cs  = col ^ ((r & 7) << 4);
                gload16(&Vt[vtbase + (size_t)r * 4096 + kv0 + (cs >> 1)],
                        vdst + wid * 2048 + c * 1024);
            }
        }
    };

    const int swz = (l31 & 7) << 4;

    stage(0, 0);
    __syncthreads();

    for (int t = 0; t < 64; ++t) {
        const int buf = t & 1;
        if (t < 63) stage(buf ^ 1, t + 1);

        const char* kb = smem + buf * 32768;
        const char* vb = kb + 16384;

        // S^T = K Q^T : two 32x32 blocks over kv
        f32x16 sc0 = Z16, sc1 = Z16;
        __builtin_amdgcn_s_setprio(1);
#pragma unroll
        for (int ks = 0; ks < 8; ++ks) {
            s16x8 k0 = *(const s16x8*)(kb + ((l31 * 256 + ks * 32 + h * 16) ^ swz));
            s16x8 k1 = *(const s16x8*)(kb + (((l31 + 32) * 256 + ks * 32 + h * 16) ^ swz));
            sc0 = mfma32(k0, qf[ks], sc0);
            sc1 = mfma32(k1, qf[ks], sc1);
        }
        __builtin_amdgcn_s_setprio(0);

        // online softmax, lane-local (tree reductions)
        float tmx;
        {
            float tr[16];
#pragma unroll
            for (int i = 0; i < 16; ++i) tr[i] = fmaxf(sc0[i], sc1[i]);
#pragma unroll
            for (int s = 8; s > 0; s >>= 1)
#pragma unroll
                for (int i = 0; i < s; ++i) tr[i] = fmaxf(tr[i], tr[i + s]);
            tmx = tr[0];
        }
        tmx = fmaxf(tmx, __shfl_xor(tmx, 32, 64));

        if (!__all(tmx - m <= 8.0f)) {             // defer-max (THR=8 in log2)
            const float mnew = fmaxf(m, tmx);
            const float f = exp2f(m - mnew);
            lsum *= f;
            accO[0] *= f; accO[1] *= f; accO[2] *= f; accO[3] *= f;
            m = mnew;
        }

        float p[32];
#pragma unroll
        for (int i = 0; i < 16; ++i) p[i] = exp2f(sc0[i] - m);
#pragma unroll
        for (int i = 0; i < 16; ++i) p[16 + i] = exp2f(sc1[i] - m);
        float ps;
        {
            float ts[16];
#pragma unroll
            for (int i = 0; i < 16; ++i) ts[i] = p[i] + p[16 + i];
#pragma unroll
            for (int s = 8; s > 0; s >>= 1)
#pragma unroll
                for (int i = 0; i < s; ++i) ts[i] += ts[i + s];
            ps = ts[0];
        }
        ps += __shfl_xor(ps, 32, 64);
        lsum += ps;

        // pack P -> bf16 B-fragments (kv-major), 16 cvt_pk + 8 permlane32_swap
        s16x8 pb[4];
#pragma unroll
        for (int g = 0; g < 4; ++g) {
            int a0 = cvtpk(p[g * 8 + 0], p[g * 8 + 1]);
            int a1 = cvtpk(p[g * 8 + 2], p[g * 8 + 3]);
            int b0 = cvtpk(p[g * 8 + 4], p[g * 8 + 5]);
            int b1 = cvtpk(p[g * 8 + 6], p[g * 8 + 7]);
            plswap(a0, b0); plswap(a1, b1);
            i32x4 w = {a0, a1, b0, b1};
            pb[g] = __builtin_bit_cast(s16x8, w);
        }

        // O^T += V^T P
        __builtin_amdgcn_s_setprio(1);
#pragma unroll
        for (int mf = 0; mf < 4; ++mf) {
            const int rowb = (mf * 32 + l31) * 128;
#pragma unroll
            for (int ks = 0; ks < 4; ++ks) {
                s16x8 vf = *(const s16x8*)(vb + ((rowb + ks * 32 + h * 16) ^ swz));
                accO[mf] = mfma32(vf, pb[ks], accO[mf]);
            }
        }
        __builtin_amdgcn_s_setprio(0);

        __syncthreads();
    }

    // epilogue: per-wave LDS transpose, coalesced write
    const float invl = 1.0f / lsum;
    accO[0] *= invl; accO[1] *= invl; accO[2] *= invl; accO[3] *= invl;

    unsigned short* tw = (unsigned short*)smem + wid * 1088;   // [32][34] shorts
    const int bb = bh >> 4, hh = bh & 15;
    const size_t cbase = ((size_t)(bb * 4096 + qt * 256 + wid * 32 + l31)) * 2048 + hh * 128;
#pragma unroll
    for (int mf = 0; mf < 4; ++mf) {
#pragma unroll
        for (int reg = 0; reg < 16; ++reg) {
            int d = (reg & 3) + 8 * (reg >> 2) + 4 * h;
            tw[d * 34 + l31] = f2bf(accO[mf][reg]);
        }
        s16x8 o0, o1;
#pragma unroll
        for (int dd = 0; dd < 8; ++dd) {
            o0[dd] = (short)tw[(h * 16 + dd) * 34 + l31];
            o1[dd] = (short)tw[(h * 16 + 8 + dd) * 34 + l31];
        }
        *(s16x8*)&ctx[cbase + mf * 32 + h * 16]     = o0;
        *(s16x8*)&ctx[cbase + mf * 32 + h * 16 + 8] = o1;
    }
}

extern "C" void kernel_launch(void* const* d_in, const int* in_sizes, int n_in,
                              void* d_out, int out_size, void* d_ws, size_t ws_size,
                              hipStream_t stream)
{
    (void)in_sizes; (void)n_in; (void)out_size;
    const float* X  = (const float*)d_in[0];
    const float* Wq = (const float*)d_in[1];
    const float* Wk = (const float*)d_in[2];
    const float* Wv = (const float*)d_in[3];
    const float* Wo = (const float*)d_in[4];

    char* ws = (char*)d_ws;
    const size_t TBL  = 2097152;     // cos+sin tables (2 x 1 MB)
    const size_t HBUF = 67108864;    // one bf16 [B,H,S,DH]-sized buffer (64 MB)
    const size_t WBUF = 8388608;     // one bf16 [2048][2048] weight (8 MB)
    const size_t SX   = 33554432;    // X elements
    const size_t SW   = 4194304;     // W elements

    float* cosb = (float*)ws;
    float* sinb = (float*)(ws + 1048576);

    const float QSCALE = 0.12751763f;   // (1/sqrt(128)) * log2(e)
    dim3 gg(128, 16), blk(256);

    rope_table_kernel<<<dim3(4096), dim3(64), 0, stream>>>(cosb, sinb);

    if (ws_size >= TBL + HBUF + 4 * WBUF + 4 * HBUF) {
        // ---- tier A: everything in ws, bf16 gload path everywhere ----
        unsigned short* Xb  = (unsigned short*)(ws + TBL);
        unsigned short* Wb0 = (unsigned short*)(ws + TBL + HBUF);
        unsigned short* Qb  = (unsigned short*)(ws + TBL + HBUF + 4 * WBUF);
        unsigned short* Kb  = Qb + SX;
        unsigned short* Vtb = Kb + SX;
        unsigned short* Cb  = Vtb + SX;
        const float* Wsrc[4] = {Wq, Wk, Wv, Wo};
        cvt_kernel<<<dim3(2048), blk, 0, stream>>>(X, Xb, (int)(SX / 8));
        for (int w = 0; w < 4; ++w)
            cvt_kernel<<<dim3(1024), blk, 0, stream>>>(Wsrc[w], Wb0 + w * SW, (int)(SW / 8));
        gemm_kernel<true, true, 0><<<gg, blk, 0, stream>>>(Xb, Wb0,          Qb, cosb, sinb, QSCALE);
        gemm_kernel<true, true, 0><<<gg, blk, 0, stream>>>(Xb, Wb0 + SW,     Kb, cosb, sinb, 1.0f);
        gemm_kernel<true, true, 1><<<gg, blk, 0, stream>>>(Xb, Wb0 + 2 * SW, Vtb, cosb, sinb, 1.0f);
        attn_kernel<<<dim3(16, 64), dim3(512), 0, stream>>>(Qb, Kb, Vtb, Cb);
        gemm_kernel<true, true, 2><<<gg, blk, 0, stream>>>(Cb, Wb0 + 3 * SW, d_out, cosb, sinb, 1.0f);
    } else if (ws_size >= TBL + HBUF + 4 * WBUF + HBUF) {
        // ---- tier B: Q,K parked in d_out; Cb shares the Xb region (X dead after V) ----
        unsigned short* Xb  = (unsigned short*)(ws + TBL);           // also Cb
        unsigned short* Wb0 = (unsigned short*)(ws + TBL + HBUF);
        unsigned short* Vtb = (unsigned short*)(ws + TBL + HBUF + 4 * WBUF);
        unsigned short* Qb  = (unsigned short*)d_out;
        unsigned short* Kb  = Qb + SX;
        unsigned short* Cb  = Xb;
        const float* Wsrc[4] = {Wq, Wk, Wv, Wo};
        cvt_kernel<<<dim3(2048), blk, 0, stream>>>(X, Xb, (int)(SX / 8));
        for (int w = 0; w < 4; ++w)
            cvt_kernel<<<dim3(1024), blk, 0, stream>>>(Wsrc[w], Wb0 + w * SW, (int)(SW / 8));
        gemm_kernel<true, true, 0><<<gg, blk, 0, stream>>>(Xb, Wb0,          Qb, cosb, sinb, QSCALE);
        gemm_kernel<true, true, 0><<<gg, blk, 0, stream>>>(Xb, Wb0 + SW,     Kb, cosb, sinb, 1.0f);
        gemm_kernel<true, true, 1><<<gg, blk, 0, stream>>>(Xb, Wb0 + 2 * SW, Vtb, cosb, sinb, 1.0f);
        attn_kernel<<<dim3(16, 64), dim3(512), 0, stream>>>(Qb, Kb, Vtb, Cb);
        gemm_kernel<true, true, 2><<<gg, blk, 0, stream>>>(Cb, Wb0 + 3 * SW, d_out, cosb, sinb, 1.0f);
    } else {
        // ---- tier C: legacy path (f32 staging in-kernel), Q,K in d_out ----
        unsigned short* Vtb = (unsigned short*)(ws + TBL);
        unsigned short* Cb  = (unsigned short*)(ws + TBL + HBUF);
        unsigned short* Qb  = (unsigned short*)d_out;
        unsigned short* Kb  = Qb + SX;
        gemm_kernel<false, false, 0><<<gg, blk, 0, stream>>>(X, Wq, Qb, cosb, sinb, QSCALE);
        gemm_kernel<false, false, 0><<<gg, blk, 0, stream>>>(X, Wk, Kb, cosb, sinb, 1.0f);
        gemm_kernel<false, false, 1><<<gg, blk, 0, stream>>>(X, Wv, Vtb, cosb, sinb, 1.0f);
        attn_kernel<<<dim3(16, 64), dim3(512), 0, stream>>>(Qb, Kb, Vtb, Cb);
        gemm_kernel<true, false, 2><<<gg, blk, 0, stream>>>(Cb, Wo, d_out, cosb, sinb, 1.0f);
    }
}